// Round 6
// baseline (225.344 us; speedup 1.0000x reference)
//
#include <hip/hip_runtime.h>
#include <hip/hip_bf16.h>

#define SIZE 6144
#define DDIM 2048
#define BHALF 2048
#define BIJ 4096
#define NT2 24   // 6144 / 256 tiles per dim
#define NKT 32   // 2048 / 64 K-tiles

typedef __attribute__((ext_vector_type(8))) short bf16x8;
typedef __attribute__((ext_vector_type(4))) float f32x4;
typedef __attribute__((ext_vector_type(4))) unsigned int u32x4;

__device__ __forceinline__ float block_reduce_sum(float v, float* red) {
    #pragma unroll
    for (int off = 32; off; off >>= 1) v += __shfl_xor(v, off, 64);
    int lane = threadIdx.x & 63, wid = threadIdx.x >> 6;
    if (lane == 0) red[wid] = v;
    __syncthreads();
    float t = red[0] + red[1] + red[2] + red[3];
    __syncthreads();
    return t;
}

// One block (256 thr) per row: L2-normalize in fp32, write bf16 z, and
// dii[r] = ||z_bf16[r]||^2 so the diagonal exp term cancels consistently.
__global__ __launch_bounds__(256) void normalize_kernel(
    const float* __restrict__ ei, const float* __restrict__ ej,
    const float* __restrict__ ek,
    unsigned short* __restrict__ zb, float* __restrict__ dii)
{
    __shared__ float red[4];
    int r = blockIdx.x;
    const float* src = (r < BHALF)   ? (ei + (size_t)r * DDIM)
                     : (r < 2*BHALF) ? (ej + (size_t)(r - BHALF) * DDIM)
                                     : (ek + (size_t)(r - 2*BHALF) * DDIM);
    int t = threadIdx.x;
    float4 v0 = ((const float4*)src)[t*2];
    float4 v1 = ((const float4*)src)[t*2 + 1];
    float ss = v0.x*v0.x + v0.y*v0.y + v0.z*v0.z + v0.w*v0.w
             + v1.x*v1.x + v1.y*v1.y + v1.z*v1.z + v1.w*v1.w;
    float tot = block_reduce_sum(ss, red);
    float scale = 1.0f / fmaxf(sqrtf(tot), 1e-12f);

    float xs[8] = {v0.x, v0.y, v0.z, v0.w, v1.x, v1.y, v1.z, v1.w};
    unsigned short u[8];
    float d = 0.f;
    #pragma unroll
    for (int j = 0; j < 8; ++j) {
        __hip_bfloat16 h = __float2bfloat16(xs[j] * scale);
        u[j] = *(unsigned short*)&h;
        float f = __bfloat162float(h);
        d += f * f;
    }
    *(u32x4*)&zb[(size_t)r * DDIM + t*8] = *(u32x4*)u;
    float dtot = block_reduce_sum(d, red);
    if (t == 0) dii[r] = dtot;
}

// Deep-pipelined symmetric sim: upper-triangular 256x256 tiles (rt <= ct).
// 8 waves (2M x 4N), BK=64, fragment-linear LDS chunks [16 rows x 32 k]
// (zero-conflict ds_read_b128), dbuf by K-tile parity, 2 super-phases per
// K-tile with counted vmcnt(8) (~1.5 K-tiles of staging lead), raw barriers,
// setprio around the MFMA cluster.
//
// Safety ledger (per super-phase sp of K-tile k):
//   sp0: vmcnt(8) retires (k)ks0 [issued at (k-2)sp1; newer = (k)ks1 4 + (k+1)ks0 4].
//        barrier. stage (k+1)ks1 -> buf (k+1)&1 [prev contents (k-1)ks1 read at
//        (k-1)sp1, all waves past this barrier]. read (k)ks0 frags. 32 MFMA.
//   sp1: vmcnt(8) retires (k)ks1 [issued (k-1)sp0; newer = (k+1)ks0 4 + (k+1)ks1 4].
//        barrier [=> all waves done reading (k)ks0]. stage (k+2)ks0 -> buf k&1 ks0
//        [just-freed chunks]. read (k)ks1 frags. 32 MFMA.
// Tail: k=31 sp0 -> vmcnt(4), sp1 -> vmcnt(0); stages skipped when target > 31.
__global__ __launch_bounds__(512, 2) void simexp_kernel(
    const unsigned short* __restrict__ zb, float* __restrict__ S)
{
    // [buf][half h][chunk f][ksub][512 shorts = 64 lanes x 8 bf16] = 64 KiB each
    __shared__ short Ab[2][2][8][2][512];
    __shared__ short Bb[2][2][8][2][512];

    // triangular decode: bid -> (rt, ct), ct >= rt
    int rem = blockIdx.x;
    int rt = 0, width = NT2;
    while (rem >= width) { rem -= width; ++rt; --width; }
    const int ct = rt + rem;

    const int tid  = threadIdx.x;
    const int lane = tid & 63;
    const int w    = tid >> 6;        // wave 0..7
    const int wr   = w >> 2;          // 0..1  (M half)
    const int wc   = w & 3;           // 0..3  (N quarter: 64 cols)
    const int bh   = wc >> 1;         // B half this wave reads
    const int rowA0 = rt * 256, colB0 = ct * 256;
    const int l15 = lane & 15, l4 = lane >> 4;

    // staging duty: wave w stages half h = w>>2, chunks f = (w&3)*2 + {0,1}
    const int sh = w >> 2, sf = (w & 3) * 2;
    const size_t aC0 = (size_t)(rowA0 + sh*128 + sf*16 + l15) * DDIM + l4*8;
    const size_t aC1 = aC0 + (size_t)16 * DDIM;
    const size_t bC0 = (size_t)(colB0 + sh*128 + sf*16 + l15) * DDIM + l4*8;
    const size_t bC1 = bC0 + (size_t)16 * DDIM;

#define GLDS(gofs, dst)                                                      \
    __builtin_amdgcn_global_load_lds(                                        \
        (const __attribute__((address_space(1))) void*)(zb + (gofs)),        \
        (__attribute__((address_space(3))) void*)(dst), 16, 0, 0)

    // stage (kt, ks) chunk-pair for A and B (4 loads/wave)
#define STAGE_AB(kt, ks) do {                                                \
    const size_t ko = (size_t)(kt)*64 + (ks)*32;                             \
    GLDS(aC0 + ko, &Ab[(kt)&1][sh][sf][ks][0]);                              \
    GLDS(aC1 + ko, &Ab[(kt)&1][sh][sf + 1][ks][0]);                          \
    GLDS(bC0 + ko, &Bb[(kt)&1][sh][sf][ks][0]);                              \
    GLDS(bC1 + ko, &Bb[(kt)&1][sh][sf + 1][ks][0]);                          \
} while (0)

    f32x4 acc[8][4];
    #pragma unroll
    for (int m = 0; m < 8; ++m)
        #pragma unroll
        for (int n = 0; n < 4; ++n)
            acc[m][n] = (f32x4){0.f, 0.f, 0.f, 0.f};

    // prologue: (0)ks0, (0)ks1, (1)ks0  -> 12 loads/wave
    STAGE_AB(0, 0);
    STAGE_AB(0, 1);
    STAGE_AB(1, 0);

#define SUPER_PHASE(k, ks)                                                   \
    {                                                                        \
        bf16x8 afr[8], bfr[4];                                               \
        _Pragma("unroll")                                                    \
        for (int m = 0; m < 8; ++m)                                          \
            afr[m] = *(const bf16x8*)&Ab[(k)&1][wr][m][ks][lane*8];          \
        _Pragma("unroll")                                                    \
        for (int n = 0; n < 4; ++n)                                          \
            bfr[n] = *(const bf16x8*)&Bb[(k)&1][bh][(wc&1)*4 + n][ks][lane*8];\
        __builtin_amdgcn_s_setprio(1);                                       \
        _Pragma("unroll")                                                    \
        for (int m = 0; m < 8; ++m)                                          \
            _Pragma("unroll")                                                \
            for (int n = 0; n < 4; ++n)                                      \
                acc[m][n] = __builtin_amdgcn_mfma_f32_16x16x32_bf16(         \
                    afr[m], bfr[n], acc[m][n], 0, 0, 0);                     \
        __builtin_amdgcn_s_setprio(0);                                       \
    }

    for (int k = 0; k < NKT; ++k) {
        // ---- super-phase 0 (ksub 0)
        if (k < NKT - 1) { asm volatile("s_waitcnt vmcnt(8)" ::: "memory"); }
        else             { asm volatile("s_waitcnt vmcnt(4)" ::: "memory"); }
        __builtin_amdgcn_s_barrier();
        if (k < NKT - 1) STAGE_AB(k + 1, 1);
        SUPER_PHASE(k, 0);
        // ---- super-phase 1 (ksub 1)
        if (k < NKT - 1) { asm volatile("s_waitcnt vmcnt(8)" ::: "memory"); }
        else             { asm volatile("s_waitcnt vmcnt(0)" ::: "memory"); }
        __builtin_amdgcn_s_barrier();
        if (k < NKT - 2) STAGE_AB(k + 2, 0);
        SUPER_PHASE(k, 1);
    }

    // exp in-register (reused for both row- and col-sums)
    #pragma unroll
    for (int m = 0; m < 8; ++m)
        #pragma unroll
        for (int n = 0; n < 4; ++n)
            #pragma unroll
            for (int q = 0; q < 4; ++q)
                acc[m][n][q] = __expf(10.0f * acc[m][n][q]);

    // ---- row-sums: D row = wr*128 + m*16 + (lane>>4)*4 + q, col = wc*64 + n*16 + (lane&15)
    {
        float rs[8][4];
        #pragma unroll
        for (int m = 0; m < 8; ++m)
            #pragma unroll
            for (int q = 0; q < 4; ++q) {
                float s = 0.f;
                #pragma unroll
                for (int n = 0; n < 4; ++n) s += acc[m][n][q];
                rs[m][q] = s;
            }
        #pragma unroll
        for (int off = 1; off < 16; off <<= 1)
            #pragma unroll
            for (int m = 0; m < 8; ++m)
                #pragma unroll
                for (int q = 0; q < 4; ++q)
                    rs[m][q] += __shfl_xor(rs[m][q], off, 64);

        if ((lane & 15) == 0) {
            float* St = S + ((ct < BIJ / 256) ? 0 : SIZE);
            int rq = l4 * 4;
            #pragma unroll
            for (int m = 0; m < 8; ++m)
                #pragma unroll
                for (int q = 0; q < 4; ++q)
                    atomicAdd(&St[rowA0 + wr*128 + m*16 + rq + q], rs[m][q]);
        }
    }

    // ---- col-sums (transpose contribution), off-diagonal tiles only
    if (rt != ct) {
        float cs[4];
        #pragma unroll
        for (int n = 0; n < 4; ++n) {
            float s = 0.f;
            #pragma unroll
            for (int m = 0; m < 8; ++m)
                #pragma unroll
                for (int q = 0; q < 4; ++q) s += acc[m][n][q];
            cs[n] = s;
        }
        #pragma unroll
        for (int off = 16; off < 64; off <<= 1)
            #pragma unroll
            for (int n = 0; n < 4; ++n)
                cs[n] += __shfl_xor(cs[n], off, 64);

        if (lane < 16) {
            float* St = S + ((rt < BIJ / 256) ? 0 : SIZE);
            #pragma unroll
            for (int n = 0; n < 4; ++n)
                atomicAdd(&St[colB0 + wc*64 + n*16 + lane], cs[n]);
        }
    }
}

__global__ void zero_kernel(float* __restrict__ p, int n) {
    int i = blockIdx.x * 256 + threadIdx.x;
    if (i < n) p[i] = 0.f;
}

// Single block: per-row loss terms, total, write scalar.
__global__ __launch_bounds__(256) void loss_kernel(
    const float* __restrict__ S, const float* __restrict__ dii,
    float* __restrict__ out)
{
    __shared__ float red[4];
    float local = 0.f;
    const float c1 = logf((float)(BIJ - 1));
    const float c2 = logf((float)(BHALF - 1));
    for (int r = threadIdx.x; r < SIZE; r += 256) {
        float s1 = S[r], s2 = S[SIZE + r];
        float eii = __expf(10.0f * dii[r]);
        float denom = s1 + s2 - eii;
        float num, c;
        if (r < BIJ) { num = s1 - eii; c = c1; }
        else         { num = s2 - eii; c = c2; }
        local += logf(denom) - logf(num) + c;
    }
    float tot = block_reduce_sum(local, red);
    if (threadIdx.x == 0) out[0] = tot / (float)SIZE;
}

extern "C" void kernel_launch(void* const* d_in, const int* in_sizes, int n_in,
                              void* d_out, int out_size, void* d_ws, size_t ws_size,
                              hipStream_t stream) {
    const float* ei = (const float*)d_in[0];
    const float* ej = (const float*)d_in[1];
    const float* ek = (const float*)d_in[2];
    float* out = (float*)d_out;

    char* ws = (char*)d_ws;
    unsigned short* zb = (unsigned short*)ws;                    // 6144*2048*2 = 25165824 B
    float* dii = (float*)(ws + 25165824);                        // 24576 B
    float* S   = (float*)(ws + 25165824 + 24576);                // 2*6144*4 = 49152 B

    zero_kernel<<<dim3(48), dim3(256), 0, stream>>>(S, 2 * SIZE);
    normalize_kernel<<<dim3(SIZE), dim3(256), 0, stream>>>(ei, ej, ek, zb, dii);
    simexp_kernel<<<dim3(NT2 * (NT2 + 1) / 2), dim3(512), 0, stream>>>(zb, S);
    loss_kernel<<<dim3(1), dim3(256), 0, stream>>>(S, dii, out);
}